// Round 2
// baseline (2179.832 us; speedup 1.0000x reference)
//
#include <hip/hip_runtime.h>

// Problem constants: B=4, Cin=Cout=64, H=W=128, K=9, PAD=1. NCHW fp32.

// ---------------- prep: transpose main weights to [c][k][o], BN constants ----
__global__ __launch_bounds__(256) void prep_kernel(
    const float* __restrict__ w1, const float* __restrict__ w2,
    const float* __restrict__ g1, const float* __restrict__ be1,
    const float* __restrict__ m1, const float* __restrict__ v1,
    const float* __restrict__ g2, const float* __restrict__ be2,
    const float* __restrict__ m2, const float* __restrict__ v2,
    float* __restrict__ wt1, float* __restrict__ wt2,
    float* __restrict__ bn1, float* __restrict__ bn2) {
  int idx = blockIdx.x * 256 + threadIdx.x;
  if (idx < 36864) {
    int o = idx & 63, ck = idx >> 6;
    int c = ck / 9, k = ck - c * 9;
    wt1[idx] = w1[(o * 64 + c) * 9 + k];     // w[o][c][k] -> wt[(c*9+k)*64+o]
  } else if (idx < 73728) {
    int i = idx - 36864;
    int o = i & 63, ck = i >> 6;
    int c = ck / 9, k = ck - c * 9;
    wt2[i] = w2[(o * 64 + c) * 9 + k];
  } else if (idx < 73728 + 64) {
    int o = idx - 73728;
    float s = g1[o] * rsqrtf(v1[o] + 1e-5f);
    bn1[o] = s;
    bn1[64 + o] = be1[o] - m1[o] * s;
  } else if (idx < 73728 + 128) {
    int o = idx - 73728 - 64;
    float s = g2[o] * rsqrtf(v2[o] + 1e-5f);
    bn2[o] = s;
    bn2[64 + o] = be2[o] - m2[o] * s;
  }
}

// ---------------- offset conv: 3x3, 64 -> 18 ch, zero pad -------------------
// Block = 256 threads = 64 pixels x 4 channel-groups (16 ch each).
// Direct neighborhood loads (L1-served, lanes coalesce along x), LDS reduce.
__global__ __launch_bounds__(256, 4) void conv_off_kernel(
    const float* __restrict__ xin, const float* __restrict__ woff,
    const float* __restrict__ boff, float* __restrict__ off) {
  __shared__ float red[256 * 19];
  int tid = threadIdx.x;
  int pl = tid & 63;          // pixel within block
  int g = tid >> 6;           // channel group 0..3 (wave-uniform)
  int p = blockIdx.x * 64 + pl;
  int b = p >> 14, hw = p & 16383;
  int h = hw >> 7, w = hw & 127;

  float a[18];
#pragma unroll
  for (int j = 0; j < 18; ++j) a[j] = 0.f;

  int c0 = g * 16;
#pragma unroll 1
  for (int c = c0; c < c0 + 16; ++c) {
    const float* xc = xin + ((size_t)(b * 64 + c) << 14);
    float v[9];
#pragma unroll
    for (int t = 0; t < 9; ++t) {
      int yy = h + t / 3 - 1, xx = w + t % 3 - 1;
      bool ok = (yy >= 0) && (yy < 128) && (xx >= 0) && (xx < 128);
      v[t] = ok ? xc[(yy << 7) + xx] : 0.f;
    }
    const float* wb = woff + c * 9;  // woff[j][c][t] = woff[j*576 + c*9 + t]
#pragma unroll
    for (int j = 0; j < 18; ++j) {
      const float* wj = wb + j * 576;  // wave-uniform -> scalar loads
#pragma unroll
      for (int t = 0; t < 9; ++t) a[j] = fmaf(v[t], wj[t], a[j]);
    }
  }
  // reduce 4 groups
#pragma unroll
  for (int j = 0; j < 18; ++j) red[tid * 19 + j] = a[j];
  __syncthreads();
  for (int i = tid; i < 1152; i += 256) {   // 64 px * 18 j
    int pp = i & 63, j = i >> 6;
    float s = boff[j];
#pragma unroll
    for (int gg = 0; gg < 4; ++gg) s += red[(gg * 64 + pp) * 19 + j];
    int pg = blockIdx.x * 64 + pp;
    off[((((pg >> 14) * 18 + j)) << 14) + (pg & 16383)] = s;
  }
}

// ---------------- fused deformable sample + einsum + BN + ReLU --------------
// Block = 256 threads = 64 pixels x 4 channel-groups (16 ch each).
// Each thread: partial acc over its 16 input channels for all 64 outputs.
__global__ __launch_bounds__(256, 4) void dcn_main_kernel(
    const float* __restrict__ xin, const float* __restrict__ off,
    const float* __restrict__ wt, const float* __restrict__ bn,
    float* __restrict__ out) {
  __shared__ float red[256 * 33];
  int tid = threadIdx.x;
  int pl = tid & 63;
  int g = tid >> 6;            // wave-uniform channel group
  int p = blockIdx.x * 64 + pl;
  int b = p >> 14, hw = p & 16383;
  int h = hw >> 7, w = hw & 127;

  float acc[64];
#pragma unroll
  for (int o = 0; o < 64; ++o) acc[o] = 0.f;

  const float* xb = xin + ((size_t)b << 20);
  int c0 = g * 16;

#pragma unroll 1
  for (int k = 0; k < 9; ++k) {
    float dy = off[((b * 18 + 2 * k) << 14) + hw];
    float dx = off[((b * 18 + 2 * k + 1) << 14) + hw];
    float py = (float)(h + k / 3 - 1) + dy;
    float px = (float)(w + (k % 3) - 1) + dx;
    float y0f = floorf(py), x0f = floorf(px);
    float wy1 = py - y0f, wx1 = px - x0f;
    float wy0 = 1.f - wy1, wx0 = 1.f - wx1;
    int y0 = (int)y0f, x0 = (int)x0f;
    int y1 = y0 + 1, x1 = x0 + 1;
    bool vy0 = (y0 >= 0) && (y0 <= 127);
    bool vy1 = (y1 >= 0) && (y1 <= 127);
    bool vx0 = (x0 >= 0) && (x0 <= 127);
    bool vx1 = (x1 >= 0) && (x1 <= 127);
    float w00 = (vy0 && vx0) ? wy0 * wx0 : 0.f;
    float w01 = (vy0 && vx1) ? wy0 * wx1 : 0.f;
    float w10 = (vy1 && vx0) ? wy1 * wx0 : 0.f;
    float w11 = (vy1 && vx1) ? wy1 * wx1 : 0.f;
    int y0c = min(max(y0, 0), 127), y1c = min(max(y1, 0), 127);
    int x0c = min(max(x0, 0), 127), x1c = min(max(x1, 0), 127);
    int i00 = (y0c << 7) + x0c, i01 = (y0c << 7) + x1c;
    int i10 = (y1c << 7) + x0c, i11 = (y1c << 7) + x1c;

    const float* xc = xb + ((size_t)c0 << 14);
    float t00 = xc[i00], t01 = xc[i01], t10 = xc[i10], t11 = xc[i11];
#pragma unroll 2
    for (int c = c0; c < c0 + 16; ++c) {
      float s = fmaf(w00, t00, fmaf(w01, t01, fmaf(w10, t10, w11 * t11)));
      if (c < c0 + 15) {
        const float* xn = xb + ((size_t)(c + 1) << 14);
        t00 = xn[i00]; t01 = xn[i01]; t10 = xn[i10]; t11 = xn[i11];
      }
      const float* wp = wt + ((c * 9 + k) << 6);  // wave-uniform -> s_load
#pragma unroll
      for (int o = 0; o < 64; ++o) acc[o] = fmaf(s, wp[o], acc[o]);
    }
  }

  // reduce 4 groups, in two 32-output chunks (LDS 256*33 floats, +1 pad)
#pragma unroll 1
  for (int chunk = 0; chunk < 2; ++chunk) {
    int o0 = chunk * 32;
#pragma unroll
    for (int oi = 0; oi < 32; ++oi) red[tid * 33 + oi] = acc[o0 + oi];
    __syncthreads();
    for (int i = tid; i < 2048; i += 256) {   // 64 px * 32 o
      int pp = i & 63, oi = i >> 6;
      float s = red[pp * 33 + oi] + red[(64 + pp) * 33 + oi] +
                red[(128 + pp) * 33 + oi] + red[(192 + pp) * 33 + oi];
      int o = o0 + oi;
      float r = fmaf(s, bn[o], bn[64 + o]);
      int pg = blockIdx.x * 64 + pp;
      out[(((pg >> 14) * 64 + o) << 14) + (pg & 16383)] = fmaxf(r, 0.f);
    }
    __syncthreads();
  }
}

extern "C" void kernel_launch(void* const* d_in, const int* in_sizes, int n_in,
                              void* d_out, int out_size, void* d_ws, size_t ws_size,
                              hipStream_t stream) {
  const float* x      = (const float*)d_in[0];
  const float* w_off1 = (const float*)d_in[1];
  const float* b_off1 = (const float*)d_in[2];
  const float* w1     = (const float*)d_in[3];
  const float* g1     = (const float*)d_in[4];
  const float* be1    = (const float*)d_in[5];
  const float* m1     = (const float*)d_in[6];
  const float* v1     = (const float*)d_in[7];
  const float* w_off2 = (const float*)d_in[8];
  const float* b_off2 = (const float*)d_in[9];
  const float* w2     = (const float*)d_in[10];
  const float* g2     = (const float*)d_in[11];
  const float* be2    = (const float*)d_in[12];
  const float* m2     = (const float*)d_in[13];
  const float* v2     = (const float*)d_in[14];
  float* out = (float*)d_out;

  float* ws   = (float*)d_ws;
  float* wt1  = ws;                       // 36864
  float* wt2  = ws + 36864;               // 36864
  float* bn1  = ws + 73728;               // 128
  float* bn2  = ws + 73856;               // 128
  float* offb = ws + 73984;               // 4*18*16384 = 1179648
  float* hbuf = ws + 73984 + 1179648;     // 4*64*16384 = 4194304

  prep_kernel<<<289, 256, 0, stream>>>(w1, w2, g1, be1, m1, v1, g2, be2, m2, v2,
                                       wt1, wt2, bn1, bn2);

  conv_off_kernel<<<1024, 256, 0, stream>>>(x, w_off1, b_off1, offb);
  dcn_main_kernel<<<1024, 256, 0, stream>>>(x, offb, wt1, bn1, hbuf);

  conv_off_kernel<<<1024, 256, 0, stream>>>(hbuf, w_off2, b_off2, offb);
  dcn_main_kernel<<<1024, 256, 0, stream>>>(hbuf, offb, wt2, bn2, out);
}

// Round 3
// 431.171 us; speedup vs baseline: 5.0556x; 5.0556x over previous
//
#include <hip/hip_runtime.h>

// B=4, Cin=Cout=64, H=W=128, K=9, PAD=1. NCHW fp32.
//
// Workspace layout (floats):
//   wt1  @ 0       (36864)  main weights layer1, [c][og][k][oi] (og=o/16, oi=o%16)
//   wt2  @ 36864   (36864)
//   wo1  @ 73728   (11520)  offset-conv weights layer1, [c][og][t][i] (og=j/5, i=j%5, padded to 20 j)
//   wo2  @ 85248   (11520)
//   bn1  @ 96768   (128)    scale[64], shift[64]
//   bn2  @ 96896   (128)
//   offb @ 97024   (1179648)  4*18*16384
//   hbuf @ 1276672 (4194304)  4*64*16384

// ---------------- prep: weight relayouts + BN constants ---------------------
__global__ __launch_bounds__(256) void prep_kernel(
    const float* __restrict__ w1, const float* __restrict__ w2,
    const float* __restrict__ woff1, const float* __restrict__ woff2,
    const float* __restrict__ g1, const float* __restrict__ be1,
    const float* __restrict__ m1, const float* __restrict__ v1,
    const float* __restrict__ g2, const float* __restrict__ be2,
    const float* __restrict__ m2, const float* __restrict__ v2,
    float* __restrict__ ws) {
  float* wt1 = ws;
  float* wt2 = ws + 36864;
  float* wo1 = ws + 73728;
  float* wo2 = ws + 85248;
  float* bn1 = ws + 96768;
  float* bn2 = ws + 96896;
  int idx = blockIdx.x * 256 + threadIdx.x;
  if (idx < 73728) {
    int t = (idx < 36864) ? idx : idx - 36864;
    const float* w = (idx < 36864) ? w1 : w2;
    float* wt = (idx < 36864) ? wt1 : wt2;
    int oi = t & 15;
    int rest = t >> 4;             // (c*4+og)*9 + k
    int k = rest % 9;
    int cog = rest / 9;
    int og = cog & 3, c = cog >> 2;
    int o = og * 16 + oi;
    wt[t] = w[(o * 64 + c) * 9 + k];
  } else if (idx < 96768) {
    int u = idx - 73728;
    int t2 = (u < 11520) ? u : u - 11520;
    const float* w = (u < 11520) ? woff1 : woff2;
    float* wo = (u < 11520) ? wo1 : wo2;
    int i = t2 % 5;
    int v = t2 / 5;                // (c*4+og)*9 + t
    int tt = v % 9;
    int cog = v / 9;
    int og = cog & 3, c = cog >> 2;
    int j = og * 5 + i;
    wo[t2] = (j < 18) ? w[(j * 64 + c) * 9 + tt] : 0.f;
  } else if (idx < 96832) {
    int o = idx - 96768;
    float s = g1[o] * rsqrtf(v1[o] + 1e-5f);
    bn1[o] = s;
    bn1[64 + o] = be1[o] - m1[o] * s;
  } else if (idx < 96896) {
    int o = idx - 96832;
    float s = g2[o] * rsqrtf(v2[o] + 1e-5f);
    bn2[o] = s;
    bn2[64 + o] = be2[o] - m2[o] * s;
  }
}

// ---------------- offset conv: 3x3, 64 -> 18 ch, zero pad -------------------
// Block = 64 px (one row segment) x 4 o-groups (5 o each, padded to 20).
// c-outer loop: 3-row halo of plane c staged in LDS (double-buffered).
__global__ __launch_bounds__(256, 4) void conv_off_kernel(
    const float* __restrict__ xin, const float* __restrict__ wofft,
    const float* __restrict__ boff, float* __restrict__ off) {
  __shared__ float halo[2][198];   // 3 rows x 66
  int tid = threadIdx.x;
  int pxl = tid & 63;
  int og = tid >> 6;
  int ogu = __builtin_amdgcn_readfirstlane(og);   // wave-uniform -> s_loads
  int p0 = blockIdx.x * 64;
  int b = p0 >> 14, hw0 = p0 & 16383;
  int h = hw0 >> 7, w0 = hw0 & 127;

  bool sv = tid < 198;
  int r = tid / 66, cc = tid - r * 66;
  int yy = h + r - 1, xx = w0 + cc - 1;
  bool inb = sv && (yy >= 0) && (yy < 128) && (xx >= 0) && (xx < 128);
  int ofs = (yy << 7) + xx;
  const float* xb0 = xin + ((size_t)(b * 64) << 14);

  float stg = inb ? xb0[ofs] : 0.f;
  float acc[5] = {0.f, 0.f, 0.f, 0.f, 0.f};

#pragma unroll 1
  for (int c = 0; c < 64; ++c) {
    if (sv) halo[c & 1][tid] = stg;
    if (c < 63) stg = inb ? xb0[((size_t)(c + 1) << 14) + ofs] : 0.f;
    __syncthreads();
    const float* wc = wofft + (c * 4 + ogu) * 45;
#pragma unroll
    for (int t = 0; t < 9; ++t) {
      float v = halo[c & 1][(t / 3) * 66 + pxl + (t % 3)];
#pragma unroll
      for (int i = 0; i < 5; ++i) acc[i] = fmaf(v, wc[t * 5 + i], acc[i]);
    }
  }
#pragma unroll
  for (int i = 0; i < 5; ++i) {
    int j = ogu * 5 + i;
    if (j < 18)
      off[((size_t)(b * 18 + j) << 14) + hw0 + pxl] = acc[i] + boff[j];
  }
}

// ---------------- fused deformable sample + einsum + BN + ReLU --------------
// Block = 64 px x 4 o-groups (16 o each). c-outer loop; per c the block's
// 576 (px,k) samples are computed cooperatively into LDS (dbuf, 1 barrier/c),
// then each thread FMAs 9k x 16o with scalar weights.
__global__ __launch_bounds__(256, 4) void dcn_main_kernel(
    const float* __restrict__ xin, const float* __restrict__ off,
    const float* __restrict__ wt, const float* __restrict__ bn,
    float* __restrict__ out) {
  __shared__ float sbuf[2][576];
  int tid = threadIdx.x;
  int pxl = tid & 63;
  int og = tid >> 6;
  int ogu = __builtin_amdgcn_readfirstlane(og);
  int p0 = blockIdx.x * 64;
  int b = p0 >> 14, hw0 = p0 & 16383;
  int h = hw0 >> 7, w0 = hw0 & 127;
  const float* xb = xin + ((size_t)b << 20);

  // --- per-thread sampling params for up to 3 samples (s = tid + 256*j) ---
  float pw[3][4];
  int pi[3][4];
  bool act[3];
#pragma unroll
  for (int j = 0; j < 3; ++j) {
    bool a = (j < 2) || (tid < 64);
    act[j] = a;
    int s = tid + 256 * j;
    int k = s >> 6;
    if (k > 8) k = 8;
    int pxs = s & 63;
    int hw = hw0 + pxs;
    float dy = a ? off[((size_t)(b * 18 + 2 * k) << 14) + hw] : 0.f;
    float dx = a ? off[((size_t)(b * 18 + 2 * k + 1) << 14) + hw] : 0.f;
    float py = (float)(h + k / 3 - 1) + dy;
    float pxf = (float)(w0 + pxs + k % 3 - 1) + dx;
    float y0f = floorf(py), x0f = floorf(pxf);
    float wy1 = py - y0f, wx1 = pxf - x0f;
    float wy0 = 1.f - wy1, wx0 = 1.f - wx1;
    int y0 = (int)y0f, x0 = (int)x0f;
    int y1 = y0 + 1, x1 = x0 + 1;
    bool vy0 = (y0 >= 0) && (y0 <= 127);
    bool vy1 = (y1 >= 0) && (y1 <= 127);
    bool vx0 = (x0 >= 0) && (x0 <= 127);
    bool vx1 = (x1 >= 0) && (x1 <= 127);
    pw[j][0] = (vy0 && vx0) ? wy0 * wx0 : 0.f;
    pw[j][1] = (vy0 && vx1) ? wy0 * wx1 : 0.f;
    pw[j][2] = (vy1 && vx0) ? wy1 * wx0 : 0.f;
    pw[j][3] = (vy1 && vx1) ? wy1 * wx1 : 0.f;
    int y0c = min(max(y0, 0), 127), y1c = min(max(y1, 0), 127);
    int x0c = min(max(x0, 0), 127), x1c = min(max(x1, 0), 127);
    pi[j][0] = (y0c << 7) + x0c;
    pi[j][1] = (y0c << 7) + x1c;
    pi[j][2] = (y1c << 7) + x0c;
    pi[j][3] = (y1c << 7) + x1c;
  }

  // prologue: taps for c=0
  float tp[3][4];
#pragma unroll
  for (int j = 0; j < 3; ++j)
#pragma unroll
    for (int q = 0; q < 4; ++q) tp[j][q] = act[j] ? xb[pi[j][q]] : 0.f;

  float acc[16];
#pragma unroll
  for (int oi = 0; oi < 16; ++oi) acc[oi] = 0.f;

#pragma unroll 1
  for (int c = 0; c < 64; ++c) {
    // blend + stash to LDS
#pragma unroll
    for (int j = 0; j < 3; ++j) {
      if (act[j]) {
        float sval = fmaf(pw[j][0], tp[j][0],
                     fmaf(pw[j][1], tp[j][1],
                     fmaf(pw[j][2], tp[j][2], pw[j][3] * tp[j][3])));
        sbuf[c & 1][tid + 256 * j] = sval;
      }
    }
    // prefetch taps for c+1 (lands under this c's einsum)
    if (c < 63) {
      const float* xn = xb + ((size_t)(c + 1) << 14);
#pragma unroll
      for (int j = 0; j < 3; ++j)
#pragma unroll
        for (int q = 0; q < 4; ++q)
          if (act[j]) tp[j][q] = xn[pi[j][q]];
    }
    __syncthreads();
    const float* wc = wt + (c * 4 + ogu) * 144;   // [c][og][k][16], scalar
#pragma unroll
    for (int k = 0; k < 9; ++k) {
      float sval = sbuf[c & 1][k * 64 + pxl];
#pragma unroll
      for (int oi = 0; oi < 16; ++oi)
        acc[oi] = fmaf(sval, wc[k * 16 + oi], acc[oi]);
    }
  }

#pragma unroll
  for (int oi = 0; oi < 16; ++oi) {
    int o = ogu * 16 + oi;
    float rres = fmaf(acc[oi], bn[o], bn[64 + o]);
    out[((size_t)(b * 64 + o) << 14) + hw0 + pxl] = fmaxf(rres, 0.f);
  }
}

extern "C" void kernel_launch(void* const* d_in, const int* in_sizes, int n_in,
                              void* d_out, int out_size, void* d_ws, size_t ws_size,
                              hipStream_t stream) {
  const float* x      = (const float*)d_in[0];
  const float* w_off1 = (const float*)d_in[1];
  const float* b_off1 = (const float*)d_in[2];
  const float* w1     = (const float*)d_in[3];
  const float* g1     = (const float*)d_in[4];
  const float* be1    = (const float*)d_in[5];
  const float* m1     = (const float*)d_in[6];
  const float* v1     = (const float*)d_in[7];
  const float* w_off2 = (const float*)d_in[8];
  const float* b_off2 = (const float*)d_in[9];
  const float* w2     = (const float*)d_in[10];
  const float* g2     = (const float*)d_in[11];
  const float* be2    = (const float*)d_in[12];
  const float* m2     = (const float*)d_in[13];
  const float* v2     = (const float*)d_in[14];
  float* out = (float*)d_out;

  float* ws   = (float*)d_ws;
  float* wt1  = ws;
  float* wt2  = ws + 36864;
  float* wo1  = ws + 73728;
  float* wo2  = ws + 85248;
  float* bn1  = ws + 96768;
  float* bn2  = ws + 96896;
  float* offb = ws + 97024;
  float* hbuf = ws + 1276672;

  prep_kernel<<<379, 256, 0, stream>>>(w1, w2, w_off1, w_off2,
                                       g1, be1, m1, v1, g2, be2, m2, v2, ws);

  conv_off_kernel<<<1024, 256, 0, stream>>>(x, wo1, b_off1, offb);
  dcn_main_kernel<<<1024, 256, 0, stream>>>(x, offb, wt1, bn1, hbuf);

  conv_off_kernel<<<1024, 256, 0, stream>>>(hbuf, wo2, b_off2, offb);
  dcn_main_kernel<<<1024, 256, 0, stream>>>(hbuf, offb, wt2, bn2, out);
}